// Round 1
// baseline (744.178 us; speedup 1.0000x reference)
//
#include <hip/hip_runtime.h>

typedef __bf16 bf16x8 __attribute__((ext_vector_type(8)));
typedef float f32x4 __attribute__((ext_vector_type(4)));
typedef unsigned short ushort8 __attribute__((ext_vector_type(8)));

__device__ __forceinline__ unsigned short f2b(float f) {
    unsigned int u = __float_as_uint(f);
    return (unsigned short)((u + 0x7fffu + ((u >> 16) & 1u)) >> 16);  // RNE
}

// ---------------------------------------------------------------------------
// Prep: fold W_nl into W_out, emit bf16 W' in MFMA fragment order, and the
// fused bias b'[o] = b_out[o] + sum_f b_nl[f]*W_out[o,f].
// Fragment layout (flat index t = (((ct*8 + ks)*64 + lane)*8 + j)):
//   element W'[f = ks*32 + (lane>>4)*8 + j][o = ct*16 + (lane&15)]
// This order serves as the A-operand fragment (M=o, K=f) of
// mfma_f32_16x16x32_bf16 — A and B lane layouts are mirror images, so the
// same bytes that previously served as B(f,o) now serve as A(o,f).
// ---------------------------------------------------------------------------
__global__ __launch_bounds__(256) void wk_prep(
    const float* __restrict__ Wnl, const float* __restrict__ bnl,
    const float* __restrict__ Wout, const float* __restrict__ bout,
    unsigned short* __restrict__ wfrag, float* __restrict__ wbias) {
    int b = blockIdx.x, tid = threadIdx.x;
    if (b < 256) {
        int t = b * 256 + tid;
        int j = t & 7;
        int lane = (t >> 3) & 63;
        int ks = (t >> 9) & 7;
        int ct = t >> 12;                       // col-tile 0..15
        int f = ks * 32 + ((lane >> 4) << 3) + j;
        int o = ct * 16 + (lane & 15);
        float c = 0.70710678f * (Wnl[2 * f] + Wnl[2 * f + 1]);
        wfrag[t] = f2b(c * Wout[o * 256 + f]);
    } else {
        int o = tid;
        const float4* wr = (const float4*)(Wout + o * 256);
        const float4* bn = (const float4*)bnl;
        float s = 0.f;
        #pragma unroll 4
        for (int i = 0; i < 64; ++i) {
            float4 a = bn[i], b4 = wr[i];
            s += a.x * b4.x + a.y * b4.y + a.z * b4.z + a.w * b4.w;
        }
        wbias[o] = bout[o] + s;
    }
}

// ---------------------------------------------------------------------------
// Persistent streaming GEMM: M=160000, K=256, N=256.
// 256 blocks x 768 thr (12 waves) = 1 block/CU (LDS 129 KB), occupancy 12 waves.
// W' (128 KB) + bias staged into LDS ONCE; after the single __syncthreads()
// there are NO barriers — each wave independently streams ~3.3 tiles of
// 16 rows, double-buffering the next tile's x in registers while the current
// tile's 128 MFMAs run. x is read from HBM exactly once; out written once
// with dense nontemporal dwordx4 (lane holds 4 consecutive o's because W' is
// the A operand: D row = o, D col = x-row).
// ---------------------------------------------------------------------------
__global__ __launch_bounds__(768, 3) void wk_main(
    const float* __restrict__ x, const unsigned short* __restrict__ wfrag,
    const float* __restrict__ wbias, float* __restrict__ out) {
    const int tid  = threadIdx.x;
    const int lane = tid & 63;
    const int w    = tid >> 6;          // wave 0..11
    const int m    = lane & 15;
    const int quad = lane >> 4;

    __shared__ bf16x8 Wlds[8192];       // 128 KB: [ct(16)][ks(8)][lane(64)] x 8 bf16
    __shared__ f32x4  blds[64];         // 1 KB fused bias

    const int gw = blockIdx.x * 12 + w;             // global wave 0..3071
    int t        = (gw * 10000) / 3072;             // chunked contiguous tiles
    const int t1 = ((gw + 1) * 10000) / 3072;       // 3 or 4 tiles per wave

    // --- prologue: issue first x-tile loads, then stage W (hides latency) ---
    float4 buf[16];                     // 64 VGPR: 16 rows x 256 cols, 32 B/lane
    {
        const float4* xv = (const float4*)(x + ((size_t)t * 16 + m) * 256);
        #pragma unroll
        for (int ks = 0; ks < 8; ++ks) {
            buf[2 * ks]     = xv[ks * 8 + quad * 2];
            buf[2 * ks + 1] = xv[ks * 8 + quad * 2 + 1];
        }
    }
    {
        int4* dst = (int4*)Wlds;
        const int4* src = (const int4*)wfrag;
        for (int i = tid; i < 8192; i += 768) dst[i] = src[i];
        if (tid < 64) blds[tid] = ((const f32x4*)wbias)[tid];
    }
    __syncthreads();                    // the ONLY barrier

    while (true) {
        // convert current tile to bf16 A..err B-fragments (loads landed a full
        // compute-phase ago, so the implicit waitcnt here is ~free)
        bf16x8 afr[8];                  // x[row=lane&15][k=ks*32+quad*8+j]
        #pragma unroll
        for (int ks = 0; ks < 8; ++ks) {
            float4 u = buf[2 * ks], v = buf[2 * ks + 1];
            ushort8 s;
            s[0] = f2b(u.x); s[1] = f2b(u.y); s[2] = f2b(u.z); s[3] = f2b(u.w);
            s[4] = f2b(v.x); s[5] = f2b(v.y); s[6] = f2b(v.z); s[7] = f2b(v.w);
            afr[ks] = __builtin_bit_cast(bf16x8, s);
        }
        // prefetch next tile into buf while this tile computes
        const int tn = t + 1;
        if (tn < t1) {
            const float4* xv = (const float4*)(x + ((size_t)tn * 16 + m) * 256);
            #pragma unroll
            for (int ks = 0; ks < 8; ++ks) {
                buf[2 * ks]     = xv[ks * 8 + quad * 2];
                buf[2 * ks + 1] = xv[ks * 8 + quad * 2 + 1];
            }
        }
        // compute + store: D[row = o-in-tile = quad*4+i][col = xrow = m]
        float* outp = out + ((size_t)t * 16 + m) * 256 + quad * 4;
        #pragma unroll
        for (int ct = 0; ct < 16; ++ct) {
            f32x4 acc = blds[ct * 4 + quad];        // bias[o..o+3], broadcast
            #pragma unroll
            for (int ks = 0; ks < 8; ++ks)
                acc = __builtin_amdgcn_mfma_f32_16x16x32_bf16(
                    Wlds[(ct * 8 + ks) * 64 + lane], afr[ks], acc, 0, 0, 0);
            // 4 consecutive o's per lane -> dense 1KB/instr nontemporal store
            __builtin_nontemporal_store(acc, (f32x4*)(outp + ct * 16));
        }
        if (tn >= t1) break;
        t = tn;
    }
}

extern "C" void kernel_launch(void* const* d_in, const int* in_sizes, int n_in,
                              void* d_out, int out_size, void* d_ws, size_t ws_size,
                              hipStream_t stream) {
    const float* x    = (const float*)d_in[0];   // [8,20000,256]
    const float* Wnl  = (const float*)d_in[1];   // [256,2]
    const float* bnl  = (const float*)d_in[2];   // [256]
    const float* Wout = (const float*)d_in[3];   // [256,256]
    const float* bout = (const float*)d_in[4];   // [256]

    unsigned short* wfrag = (unsigned short*)d_ws;            // 65536 bf16 = 128 KB
    float* wbias = (float*)((char*)d_ws + 131072);            // 256 f32

    wk_prep<<<257, 256, 0, stream>>>(Wnl, bnl, Wout, bout, wfrag, wbias);
    wk_main<<<256, 768, 0, stream>>>(x, wfrag, wbias, (float*)d_out);
}

// Round 2
// 309.490 us; speedup vs baseline: 2.4045x; 2.4045x over previous
//
#include <hip/hip_runtime.h>

typedef __bf16 bf16x8 __attribute__((ext_vector_type(8)));
typedef float f32x4 __attribute__((ext_vector_type(4)));
typedef unsigned short ushort8 __attribute__((ext_vector_type(8)));

__device__ __forceinline__ unsigned short f2b(float f) {
    unsigned int u = __float_as_uint(f);
    return (unsigned short)((u + 0x7fffu + ((u >> 16) & 1u)) >> 16);  // RNE
}

__device__ __forceinline__ void gl_lds16(const void* g, void* l) {
    __builtin_amdgcn_global_load_lds(
        (const __attribute__((address_space(1))) unsigned int*)g,
        (__attribute__((address_space(3))) unsigned int*)l, 16, 0, 0);
}

// ---------------------------------------------------------------------------
// Prep (unchanged, correctness-proven): fold W_nl into W_out, emit bf16 W'
// in MFMA fragment order [ct][ks][lane][j], plus fused bias
// b'[o] = b_out[o] + sum_f b_nl[f]*W_out[o,f].
// ---------------------------------------------------------------------------
__global__ __launch_bounds__(256) void wk_prep(
    const float* __restrict__ Wnl, const float* __restrict__ bnl,
    const float* __restrict__ Wout, const float* __restrict__ bout,
    unsigned short* __restrict__ wfrag, float* __restrict__ wbias) {
    int b = blockIdx.x, tid = threadIdx.x;
    if (b < 256) {
        int t = b * 256 + tid;
        int j = t & 7;
        int lane = (t >> 3) & 63;
        int ks = (t >> 9) & 7;
        int ct = t >> 12;                       // col-tile 0..15
        int f = ks * 32 + ((lane >> 4) << 3) + j;
        int o = ct * 16 + (lane & 15);
        float c = 0.70710678f * (Wnl[2 * f] + Wnl[2 * f + 1]);
        wfrag[t] = f2b(c * Wout[o * 256 + f]);
    } else {
        int o = tid;
        const float4* wr = (const float4*)(Wout + o * 256);
        const float4* bn = (const float4*)bnl;
        float s = 0.f;
        #pragma unroll 4
        for (int i = 0; i < 64; ++i) {
            float4 a = bn[i], b4 = wr[i];
            s += a.x * b4.x + a.y * b4.y + a.z * b4.z + a.w * b4.w;
        }
        wbias[o] = bout[o] + s;
    }
}

// ---------------------------------------------------------------------------
// Streaming GEMM, DRAM-locality version. M=160000, K=256, N=256.
// 256 persistent blocks x 512 thr (8 waves), 1 block/CU (LDS 128 KB).
// W' lives in REGISTERS: wave w owns output cols [32w, 32w+32) = 2 col-tiles
// (32 VGPRs of A-fragments). x tiles (64 rows = 64 KB f32) are staged into a
// double-buffered LDS via global_load_lds: each wave-instruction reads one
// FULL 1-KB x row (8 consecutive fully-used 128-B lines) -> sequential DRAM
// streams, vs the previous stride-1KB half-line scatter that capped at
// 2.5 TB/s. Source chunks are XOR-swizzled (chunk ^ (row&7), line-internal)
// so LDS stays linear but fragment ds_read_b128s are bank-conflict-free.
// Raw s_barrier + counted vmcnt(16) keeps next-tile loads in flight across
// barriers (no vmcnt(0) in the main loop).
// ---------------------------------------------------------------------------
__global__ __launch_bounds__(512, 2) void wk_main(
    const float* __restrict__ x, const unsigned short* __restrict__ wfrag,
    const float* __restrict__ wbias, float* __restrict__ out) {
    const int tid  = threadIdx.x;
    const int lane = tid & 63;
    const int w    = tid >> 6;          // wave 0..7
    const int m    = lane & 15;
    const int quad = lane >> 4;
    const int swz  = m & 7;

    __shared__ float4 Xlds[2][4096];    // 2 x 64 KB, [row(64)][chunk(64)] f32x4

    const int b  = blockIdx.x;
    const int t0 = (b * 2500) >> 8;     // 64-row tiles, 2500 total
    const int t1 = ((b + 1) * 2500) >> 8;

    // --- W' fragments (2 adjacent col-tiles) + fused bias, in registers ---
    int4  Wf[2][8];
    f32x4 bias[2];
    {
        const int4* ws = (const int4*)wfrag;
        #pragma unroll
        for (int c2 = 0; c2 < 2; ++c2) {
            #pragma unroll
            for (int ks = 0; ks < 8; ++ks)
                Wf[c2][ks] = ws[(((2 * w + c2) * 8 + ks) << 6) + lane];
            bias[c2] = *(const f32x4*)(wbias + (2 * w + c2) * 16 + quad * 4);
        }
    }

    // --- staging: 8 global_load_lds(16B) per thread = one 64-row tile.
    // step s: wave w loads row r = s*8 + w fully; src chunk = lane ^ (r&7)
    // = lane ^ w (line-internal permutation, stream stays sequential).
    const char* xc = (const char*)x;
    #define STAGE(T, P)                                                        \
        {                                                                      \
            _Pragma("unroll")                                                  \
            for (int s = 0; s < 8; ++s) {                                      \
                int r = s * 8 + w;                                             \
                gl_lds16(xc + (size_t)((T) * 64 + r) * 1024 + ((lane ^ w) << 4),\
                         (void*)&Xlds[P][s * 512 + w * 64]);                   \
            }                                                                  \
        }

    // prologue: two tiles in flight, wait only for the first (counted)
    STAGE(t0, 0);
    STAGE(t0 + 1, 1);
    asm volatile("s_waitcnt vmcnt(8)" ::: "memory");   // tile t0 landed
    __builtin_amdgcn_s_barrier();
    __builtin_amdgcn_sched_barrier(0);

    int t = t0, p = 0;
    while (true) {
        // ---- compute tile t from Xlds[p] ----
        const float4* buf = (const float4*)Xlds[p];
        #pragma unroll
        for (int mt = 0; mt < 4; ++mt) {
            f32x4 a0 = bias[0], a1 = bias[1];
            const int rb = (mt * 16 + m) * 64;
            #pragma unroll
            for (int ks = 0; ks < 8; ++ks) {
                float4 u = buf[rb + ((ks * 8 + quad * 2)     ^ swz)];
                float4 v = buf[rb + ((ks * 8 + quad * 2 + 1) ^ swz)];
                ushort8 sh;
                sh[0] = f2b(u.x); sh[1] = f2b(u.y); sh[2] = f2b(u.z); sh[3] = f2b(u.w);
                sh[4] = f2b(v.x); sh[5] = f2b(v.y); sh[6] = f2b(v.z); sh[7] = f2b(v.w);
                bf16x8 afr = __builtin_bit_cast(bf16x8, sh);
                a0 = __builtin_amdgcn_mfma_f32_16x16x32_bf16(
                    __builtin_bit_cast(bf16x8, Wf[0][ks]), afr, a0, 0, 0, 0);
                a1 = __builtin_amdgcn_mfma_f32_16x16x32_bf16(
                    __builtin_bit_cast(bf16x8, Wf[1][ks]), afr, a1, 0, 0, 0);
            }
            // D[row=o][col=xrow]: lane holds o = ct*16+quad*4..+3, xrow = m
            float* op = out + (size_t)(t * 64 + mt * 16 + m) * 256 + w * 32 + quad * 4;
            *(f32x4*)op        = a0;       // cols 32w    .. 32w+15 (of its ct)
            *(f32x4*)(op + 16) = a1;       // wave covers full 128 B/row
        }

        if (++t == t1) break;
        __builtin_amdgcn_s_barrier();      // all waves done reading Xlds[p]
        __builtin_amdgcn_sched_barrier(0);
        if (t + 1 < t1) {
            STAGE(t + 1, p);               // refill the buffer just drained
            // outstanding (old->new): loads(t)=8, stores(t-1)=8, loads(t+1)=8
            // vmcnt(16) => tile t's loads retired; younger 16 stay in flight
            asm volatile("s_waitcnt vmcnt(16)" ::: "memory");
        } else {
            asm volatile("s_waitcnt vmcnt(8)" ::: "memory");  // no new stage
        }
        __builtin_amdgcn_s_barrier();      // tile t visible to all waves
        __builtin_amdgcn_sched_barrier(0);
        p ^= 1;
    }
    #undef STAGE
}

extern "C" void kernel_launch(void* const* d_in, const int* in_sizes, int n_in,
                              void* d_out, int out_size, void* d_ws, size_t ws_size,
                              hipStream_t stream) {
    const float* x    = (const float*)d_in[0];   // [8,20000,256]
    const float* Wnl  = (const float*)d_in[1];   // [256,2]
    const float* bnl  = (const float*)d_in[2];   // [256]
    const float* Wout = (const float*)d_in[3];   // [256,256]
    const float* bout = (const float*)d_in[4];   // [256]

    unsigned short* wfrag = (unsigned short*)d_ws;            // 65536 bf16 = 128 KB
    float* wbias = (float*)((char*)d_ws + 131072);            // 256 f32

    wk_prep<<<257, 256, 0, stream>>>(Wnl, bnl, Wout, bout, wfrag, wbias);
    wk_main<<<256, 512, 0, stream>>>(x, wfrag, wbias, (float*)d_out);
}

// Round 4
// 302.374 us; speedup vs baseline: 2.4611x; 1.0235x over previous
//
#include <hip/hip_runtime.h>

typedef __bf16 bf16x8 __attribute__((ext_vector_type(8)));
typedef __bf16 bf16x4 __attribute__((ext_vector_type(4)));
typedef float f32x4 __attribute__((ext_vector_type(4)));

__device__ __forceinline__ unsigned short f2b(float f) {
    unsigned int u = __float_as_uint(f);
    return (unsigned short)((u + 0x7fffu + ((u >> 16) & 1u)) >> 16);  // RNE
}

// ---------------------------------------------------------------------------
// Prep (unchanged, correctness-proven): fold W_nl into W_out, emit bf16 W'
// in MFMA fragment order [ct][ks][lane][j], plus fused bias
// b'[o] = b_out[o] + sum_f b_nl[f]*W_out[o,f].
// ---------------------------------------------------------------------------
__global__ __launch_bounds__(256) void wk_prep(
    const float* __restrict__ Wnl, const float* __restrict__ bnl,
    const float* __restrict__ Wout, const float* __restrict__ bout,
    unsigned short* __restrict__ wfrag, float* __restrict__ wbias) {
    int b = blockIdx.x, tid = threadIdx.x;
    if (b < 256) {
        int t = b * 256 + tid;
        int j = t & 7;
        int lane = (t >> 3) & 63;
        int ks = (t >> 9) & 7;
        int ct = t >> 12;                       // col-tile 0..15
        int f = ks * 32 + ((lane >> 4) << 3) + j;
        int o = ct * 16 + (lane & 15);
        float c = 0.70710678f * (Wnl[2 * f] + Wnl[2 * f + 1]);
        wfrag[t] = f2b(c * Wout[o * 256 + f]);
    } else {
        int o = tid;
        const float4* wr = (const float4*)(Wout + o * 256);
        const float4* bn = (const float4*)bnl;
        float s = 0.f;
        #pragma unroll 4
        for (int i = 0; i < 64; ++i) {
            float4 a = bn[i], b4 = wr[i];
            s += a.x * b4.x + a.y * b4.y + a.z * b4.z + a.w * b4.w;
        }
        wbias[o] = bout[o] + s;
    }
}

// ---------------------------------------------------------------------------
// Round 4 = round 3 resubmitted (round-3 bench was an infra failure, not a
// kernel failure; theory unmeasured, so no blind mutation).
// Convert-once bf16 LDS staging + 2 blocks/CU.
// M=160000 rows in 5000 tiles of 32 rows. 512 persistent blocks x 512 thr
// (8 waves); LDS/block = 2 x (32 rows x 576 B) = 36 KB -> 2 blocks/CU
// (16 waves) so independent blocks fill each other's stalls (round-2 failure:
// 1 lockstep block/CU, 18% occupancy, all pipes idle).
// Staging: reg-path f32 loads -> ONE f32->bf16 convert per element per CU
// (round 2 converted 8x redundantly, VALU 23%) -> ds_write into [row][k]
// bf16 rows padded to 576 B. Padding kills the imbalance: each ds_read_b128
// lands exactly 8 lanes x 4 dwords on every one of the 32 banks (= the b128
// throughput floor), ds_write_b64 is 512 B contiguous (free 2-way).
// W' fragments stay in registers (wave owns 2 col-tiles, 64 VGPR).
// One lgkmcnt(0)+s_barrier per tile, double-buffered LDS; next-tile global
// loads issued pre-barrier so HBM latency hides under compute (T14).
// ---------------------------------------------------------------------------
__global__ __launch_bounds__(512, 4) void wk_main(
    const float* __restrict__ x, const unsigned short* __restrict__ wfrag,
    const float* __restrict__ wbias, float* __restrict__ out) {
    const int tid  = threadIdx.x;
    const int lane = tid & 63;
    const int w    = tid >> 6;          // wave 0..7
    const int m    = lane & 15;
    const int quad = lane >> 4;

    __shared__ char Xlds[2][18432];     // [p][row(32)][576 B: 512 data + 64 pad]

    const int b  = blockIdx.x;
    const int t0 = (b * 5000) >> 9;     // 32-row tiles, 5000 total
    const int t1 = ((b + 1) * 5000) >> 9;

    // --- W' fragments (2 adjacent col-tiles) + fused bias, in registers ---
    int4  Wf[2][8];
    f32x4 bias[2];
    {
        const int4* ws = (const int4*)wfrag;
        #pragma unroll
        for (int c2 = 0; c2 < 2; ++c2) {
            #pragma unroll
            for (int ks = 0; ks < 8; ++ks)
                Wf[c2][ks] = ws[(((2 * w + c2) * 8 + ks) << 6) + lane];
            bias[c2] = *(const f32x4*)(wbias + (2 * w + c2) * 16 + quad * 4);
        }
    }

    // --- staging regs: 4 x f32x4 = 16 VGPR (wave w, step s -> row s*8+w,
    //     lane covers 16-B chunk `lane` of the 1-KB row) ---
    f32x4 sbuf[4];
    #define LOADT(T)                                                          \
        {                                                                     \
            const f32x4* xt = (const f32x4*)x + (size_t)(T) * 2048;           \
            _Pragma("unroll")                                                 \
            for (int s = 0; s < 4; ++s)                                       \
                sbuf[s] = xt[s * 512 + w * 64 + lane];                        \
        }

    LOADT(t0);
    int p = 0;
    for (int t = t0; t < t1; ++t) {
        // ---- convert once, write bf16 rows into Xlds[p] ----
        {
            char* dst = Xlds[p] + w * 576 + lane * 8;
            #pragma unroll
            for (int s = 0; s < 4; ++s) {
                f32x4 u = sbuf[s];
                bf16x4 h;
                h[0] = (__bf16)u[0]; h[1] = (__bf16)u[1];
                h[2] = (__bf16)u[2]; h[3] = (__bf16)u[3];
                *(bf16x4*)(dst + s * 4608) = h;     // row s*8+w, 8 B/lane
            }
        }
        // issue next tile's loads now; they fly under compute(t)
        if (t + 1 < t1) LOADT(t + 1);
        asm volatile("s_waitcnt lgkmcnt(0)" ::: "memory");  // writes visible
        __builtin_amdgcn_s_barrier();
        __builtin_amdgcn_sched_barrier(0);

        // ---- compute tile t from Xlds[p] ----
        const char* src = Xlds[p] + m * 576 + quad * 16;
        #pragma unroll
        for (int mt = 0; mt < 2; ++mt) {
            f32x4 a0 = bias[0], a1 = bias[1];
            #pragma unroll
            for (int ks = 0; ks < 8; ++ks) {
                bf16x8 afr = *(const bf16x8*)(src + mt * 9216 + ks * 64);
                a0 = __builtin_amdgcn_mfma_f32_16x16x32_bf16(
                    __builtin_bit_cast(bf16x8, Wf[0][ks]), afr, a0, 0, 0, 0);
                a1 = __builtin_amdgcn_mfma_f32_16x16x32_bf16(
                    __builtin_bit_cast(bf16x8, Wf[1][ks]), afr, a1, 0, 0, 0);
            }
            // D[row=o][col=xrow]; wave covers full 128 B of its row-pair
            float* op = out + (size_t)(t * 32 + mt * 16 + m) * 256 + w * 32 + quad * 4;
            *(f32x4*)op        = a0;
            *(f32x4*)(op + 16) = a1;
        }
        p ^= 1;
    }
    #undef LOADT
}

extern "C" void kernel_launch(void* const* d_in, const int* in_sizes, int n_in,
                              void* d_out, int out_size, void* d_ws, size_t ws_size,
                              hipStream_t stream) {
    const float* x    = (const float*)d_in[0];   // [8,20000,256]
    const float* Wnl  = (const float*)d_in[1];   // [256,2]
    const float* bnl  = (const float*)d_in[2];   // [256]
    const float* Wout = (const float*)d_in[3];   // [256,256]
    const float* bout = (const float*)d_in[4];   // [256]

    unsigned short* wfrag = (unsigned short*)d_ws;            // 65536 bf16 = 128 KB
    float* wbias = (float*)((char*)d_ws + 131072);            // 256 f32

    wk_prep<<<257, 256, 0, stream>>>(Wnl, bnl, Wout, bout, wfrag, wbias);
    wk_main<<<512, 512, 0, stream>>>(x, wfrag, wbias, (float*)d_out);
}